// Round 24
// baseline (104.913 us; speedup 1.0000x reference)
//
#include <hip/hip_runtime.h>

typedef unsigned long long u64;
typedef unsigned int u32;

namespace {
constexpr int kB = 16;
constexpr int kN = 8732;
constexpr int kC = 20;
constexpr int kRow = 25;      // 1 + C + 4
constexpr int kKeep = 300;    // NNS_K (ws stride; reference keeps 300/class)
constexpr int kSel = 200;     // selections that can matter: per-class entries at
                              // list position >= 200 have global rank >= 200 and
                              // can never appear in the top-200 output. Greedy's
                              // first 200 selections depend only on earlier
                              // selections, so stopping at 200 is exact.
constexpr int kTot = 200;     // K_TOTAL
constexpr float kConf = 0.01f;
// fl32(inter/union) > 0.45f  <=>  inter/union > 0.45f + ulp/2 (0.45f mantissa even,
// tie rounds down). kThr = 30198989 * 2^-26 exactly; 26-bit x 24-bit product
// is <= 50 bits -> exact in f64, so the f64 compare is an exact emulation.
constexpr double kThr = 0.45000000298023223876953125;

constexpr int TPB = 512;
constexpr int NW = TPB / 64;                  // 8 waves
constexpr int NBKT = 2048;                    // score buckets (bits>>15); range
                                              // for s in (0.01,1] is ~1722 bkts
constexpr int BPT = NBKT / TPB;               // 4 buckets/thread in the scan
constexpr int kPool = 512;                    // sorted pool per tranche; rank
                                              // needed for cnt=200 is ~320-360
                                              // at measured p~0.0032 (tranche
                                              // loop keeps exactness regardless)
constexpr int kFlat = kC * kKeep;             // 6000
constexpr int kNIter = (kN + TPB - 1) / TPB;  // 18
}

// exact emulation of reference: (union>0) && fl32(inter/union) > 0.45f
// (union >= 0 provable by rounding monotonicity; union==0 => inter==0 => false)
// box layout: float4 = (y1, x1, y2, x2)
__device__ __forceinline__ bool iou_gt4(const float4 a, const float aa,
                                        const float4 b, const float ba) {
  const float ty1 = fmaxf(a.x, b.x);
  const float tx1 = fmaxf(a.y, b.y);
  const float ty2 = fminf(a.z, b.z);
  const float tx2 = fminf(a.w, b.w);
  const float dy = fmaxf(__fsub_rn(ty2, ty1), 0.0f);
  const float dx = fmaxf(__fsub_rn(tx2, tx1), 0.0f);
  const float inter = __fmul_rn(dy, dx);
  const float uni = __fsub_rn(__fadd_rn(aa, ba), inter);
  return ((double)inter > kThr * (double)uni);
}

// bucket by high bits of score: monotone DESC (bucket 0 = highest scores).
// s in (0.01, 1.0]: bits>>15 in [30791, 32512] -> bkt in [0, 1721] < 2048.
__device__ __forceinline__ int bkt_of(float s) {
  return 32512 - (int)(__float_as_uint(s) >> 15);
}
// packed in-bucket key: same bucket => scores share bits[31:15], so
// (low15 desc, 16383-idx desc) == (score desc, idx asc). 15+14=29 bits.
__device__ __forceinline__ u32 key_of(float s, int idx) {
  return ((__float_as_uint(s) & 0x7FFFu) << 14) | (u32)(16383 - idx);
}
// full-order u64 merge key: (score desc, flat idx asc); 0 == empty
__device__ __forceinline__ u64 mkey(float s, u32 f) {
  return (s > 0.0f) ? ((((u64)__float_as_uint(s)) << 32) | (u64)(0xFFFFFFFFu - f))
                    : 0ull;
}

// exclusive prefix sum over hist[NBKT]; TPB threads own BPT buckets each.
__device__ int excl_scan_hist(u32* hist, u32* wsum, int tid) {
  const int base = tid * BPT;
  u32 loc[BPT];
  u32 s = 0;
#pragma unroll
  for (int i = 0; i < BPT; ++i) { loc[i] = hist[base + i]; s += loc[i]; }
  int v = (int)s;
  const int lane = tid & 63;
#pragma unroll
  for (int off = 1; off < 64; off <<= 1) {
    const int u = __shfl_up(v, off);
    if (lane >= off) v += u;
  }
  if (lane == 63) wsum[tid >> 6] = (u32)v;
  __syncthreads();
  u32 woff = 0, total = 0;
#pragma unroll
  for (int w = 0; w < NW; ++w) {
    const u32 t = wsum[w];
    total += t;
    if (w < (tid >> 6)) woff += t;
  }
  u32 run = woff + (u32)v - s;
#pragma unroll
  for (int i = 0; i < BPT; ++i) { hist[base + i] = run; run += loc[i]; }
  __syncthreads();
  return (int)total;
}

// Transpose pass: scores_t[b][c][n] + packed float4 boxes pbox[b][n].
__global__ __launch_bounds__(256) void prep_kernel(const float* __restrict__ in,
                                                   float* __restrict__ st,
                                                   float4* __restrict__ pbox) {
  const int b = blockIdx.y;
  const int n0 = blockIdx.x * 256;
  const int tid = threadIdx.x;
  const int rows = min(256, kN - n0);

  __shared__ float tile[256 * kRow];
  const float* __restrict__ src = in + ((size_t)b * kN + n0) * kRow;
  const int total = rows * kRow;
  for (int i = tid; i < total; i += 256) tile[i] = src[i];
  __syncthreads();
  if (tid < rows) {
    const int n = n0 + tid;
    const float* row = &tile[tid * kRow];
#pragma unroll
    for (int c = 0; c < kC; ++c)
      st[((size_t)b * kC + c) * kN + n] = row[1 + c];
    pbox[(size_t)b * kN + n] = make_float4(row[21], row[22], row[23], row[24]);
  }
}

// One block per (b,c) task. Phase 1 (per tranche): bucket-CDF window of top
// <=512 candidates, scatter + tiny in-bucket insertion sorts -> exact
// (score desc, idx asc) pool; boxes/areas/scores prefetched to LDS.
// Phase 2: groups of 64; all 512 threads compute sup-vs-selected + in-group
// kill rows; wave 0 resolves. Scan stops at kSel=200 selections (exact:
// later selections cannot affect the top-200 output).
template <bool X>
__global__ __launch_bounds__(TPB, 4) void nms_kernel(const float* __restrict__ in,
                                                     const float* __restrict__ st,
                                                     const float4* __restrict__ pbox,
                                                     float* __restrict__ ws_s,
                                                     float* __restrict__ ws_b) {
  const int task = blockIdx.x;
  const int b = task / kC;
  const int c = task - b * kC;
  const int tid = threadIdx.x;
  const float* __restrict__ base_in = in + (size_t)b * kN * kRow;
  const float* __restrict__ stc = st + ((size_t)b * kC + c) * kN;
  const size_t bo = (size_t)b * kN;

  __shared__ __align__(16) unsigned char ovl[12288];  // hist(8K) | pool(12K)
  __shared__ u32 skey[kPool];                         // 2 KB
  __shared__ float4 sel_box[kSel];                    // 3.2 KB
  __shared__ float sel_ar[kSel];                      // 0.8 KB
  __shared__ float sel_sc[kSel];                      // 0.8 KB
  __shared__ u32 supp8[NW * 64];                      // 2 KB
  __shared__ u64 grp8[NW * 64];                       // 4 KB
  __shared__ u32 wsum[NW];
  __shared__ int s_red[NW];
  __shared__ int s_nc;

  u32* hist = (u32*)ovl;                // 2048 * 4 = 8 KB
  float4* gbox = (float4*)ovl;          // 512 * 16 = 8 KB
  float* gar = (float*)(ovl + 8192);    // 2 KB
  float* gsc = (float*)(ovl + 10240);   // 2 KB

  const int lane = tid & 63;
  const int wid = tid >> 6;

  int cnt = 0;
  int blo = 0;
  while (cnt < kSel && blo < NBKT) {
    // ---- histogram (scores re-read from the coalesced L2-hot column) ----
    for (int i = tid; i < NBKT; i += TPB) hist[i] = 0;
    __syncthreads();
    for (int k = 0; k < kNIter; ++k) {
      const int n = tid + k * TPB;
      if (n < kN) {
        const float s = X ? stc[n] : base_in[(size_t)n * kRow + 1 + c];
        if (s > kConf) atomicAdd(&hist[bkt_of(s)], 1u);
      }
    }
    __syncthreads();
    const int ncand = excl_scan_hist(hist, wsum, tid);
    const int base = (int)hist[blo];
    if (ncand == 0 || base >= ncand) break;
    // ---- bend: max bucket bound with window count <= kPool ----
    int bestb = blo + 1;
#pragma unroll
    for (int i = 0; i < BPT; ++i) {
      const int bb = tid * BPT + i;
      if (bb > blo && (int)hist[bb] - base <= kPool) bestb = max(bestb, bb);
    }
    if (ncand - base <= kPool) bestb = NBKT;
#pragma unroll
    for (int off = 32; off; off >>= 1) bestb = max(bestb, __shfl_xor(bestb, off));
    if (lane == 0) s_red[wid] = bestb;
    __syncthreads();
    int bend = s_red[0];
#pragma unroll
    for (int w = 1; w < NW; ++w) bend = max(bend, s_red[w]);
    const int poolN =
        min(((bend == NBKT) ? ncand : (int)hist[bend]) - base, kPool);
    // ---- scatter window [blo, bend) ----
    for (int k = 0; k < kNIter; ++k) {
      const int n = tid + k * TPB;
      if (n < kN) {
        const float s = X ? stc[n] : base_in[(size_t)n * kRow + 1 + c];
        if (s > kConf) {
          const int bb = bkt_of(s);
          if (bb >= blo && bb < bend) {
            const u32 pos = atomicAdd(&hist[bb], 1u) - (u32)base;
            if (pos < (u32)kPool) skey[pos] = key_of(s, n);
          }
        }
      }
    }
    __syncthreads();
    // ---- in-bucket insertion sort (desc u32 key) ----
    for (int bb = blo + tid; bb < bend; bb += TPB) {
      int s0 = (bb == blo) ? 0 : (int)hist[bb - 1] - base;
      int e0 = (int)hist[bb] - base;
      s0 = min(s0, kPool);
      e0 = min(e0, kPool);
      for (int i = s0 + 1; i < e0; ++i) {
        const u32 kk = skey[i];
        int j = i - 1;
        while (j >= s0 && kk > skey[j]) { skey[j + 1] = skey[j]; --j; }
        skey[j + 1] = kk;
      }
    }
    __syncthreads();  // hist dead -> pool arrays overlay it
    // ---- pool prefetch: boxes, areas, scores ----
    for (int i = tid; i < poolN; i += TPB) {
      const int eidx = 16383 - (int)(skey[i] & 0x3FFFu);
      float4 bx;
      float s;
      if (X) {
        bx = pbox[bo + eidx];
        s = stc[eidx];
      } else {
        const float* r = base_in + (size_t)eidx * kRow;
        bx = make_float4(r[21], r[22], r[23], r[24]);
        s = r[1 + c];
      }
      gbox[i] = bx;
      gar[i] = __fmul_rn(__fsub_rn(bx.z, bx.x), __fsub_rn(bx.w, bx.y));
      gsc[i] = s;
    }
    __syncthreads();

    // ---- phase 2: groups of 64 ----
    int g0 = 0;
    while (cnt < kSel && g0 < poolN) {
      const int i = g0 + lane;
      u32 sup = 1u;
      u64 rowbits = 0;
      if (i < poolN) {
        sup = 0u;
        const float4 eb = gbox[i];
        const float ea = gar[i];
        for (int j = wid; j < cnt; j += NW)
          sup |= iou_gt4(eb, ea, sel_box[j], sel_ar[j]) ? 1u : 0u;
        for (int t2 = wid; t2 < lane; t2 += NW)
          rowbits |= iou_gt4(eb, ea, gbox[g0 + t2], gar[g0 + t2])
                         ? (1ull << t2)
                         : 0ull;
      }
      supp8[wid * 64 + lane] = sup;
      grp8[wid * 64 + lane] = rowbits;
      __syncthreads();  // A: partials visible
      if (tid < 64) {   // wave 0 resolve (exact sequential-greedy semantics)
        u32 sp = 0;
        u64 row = 0;
#pragma unroll
        for (int s2 = 0; s2 < NW; ++s2) {
          sp |= supp8[s2 * 64 + tid];
          row |= grp8[s2 * 64 + tid];
        }
        const u64 pend = __ballot(sp == 0u);
        u64 acc = 0;
        int nc = cnt;
        if (cnt + __popcll(pend) <= kSel) {
          // cap-free: mass-accept unconstrained (row==0) lanes; serial walk
          // only the constrained ones (ascending == rank order).
          const u64 consb = __ballot(row != 0ull);
          acc = pend & ~consb;
          u64 rem = pend & consb;
          while (rem != 0ull) {
            const int cur = __ffsll(rem) - 1;
            const u64 cb = 1ull << cur;
            const u64 rcur = __shfl(row, cur);  // row bits only cover earlier lanes
            if ((rcur & acc) == 0ull) acc |= cb;
            rem &= ~cb;
          }
          nc = cnt + (int)__popcll(acc);
        } else {
          // near the kSel cap: exact capped serial walk (accepts in rank
          // order; the first 200 accepts are exactly greedy's first 200)
          u64 pend2 = pend;
          while (pend2 != 0ull && nc < kSel) {
            const int cur = __ffsll(pend2) - 1;
            const u64 cb = 1ull << cur;
            acc |= cb;
            ++nc;
            const u64 killed = __ballot(((row >> cur) & 1ull) != 0ull);
            pend2 &= ~(killed | cb);
          }
        }
        if ((acc >> tid) & 1ull) {
          const int slot = cnt + (int)__popcll(acc & ((1ull << tid) - 1ull));
          const int ii = g0 + tid;
          sel_box[slot] = gbox[ii];
          sel_ar[slot] = gar[ii];
          sel_sc[slot] = gsc[ii];
        }
        if (tid == 0) s_nc = nc;
      }
      __syncthreads();  // B: sel + s_nc visible
      cnt = s_nc;
      g0 += 64;
    }
    blo = bend;
  }

  // ---- final writeout (slots [cnt, 300) = empty; topk reads only [0,200)) ----
  float* __restrict__ out_s = ws_s + (size_t)task * kKeep;
  float* __restrict__ out_b = ws_b + (size_t)task * kKeep * 4;
  for (int i = tid; i < kKeep; i += TPB) {
    if (i < cnt) {
      out_s[i] = sel_sc[i];
      *(float4*)&out_b[(size_t)i * 4] = sel_box[i];
    } else {
      out_s[i] = -1.0f;
    }
  }
}

// One 256-thread block per (b, c): top-200 by merge-rank with the 19
// cross-class binary searches of each candidate done by DIFFERENT threads
// (independent, latency-overlapped), ranks summed via LDS atomicAdd.
// Only the first kTot entries per class can reach the top-200 (position i
// has i better elements in its own list). Keys are a strict total order
// (score desc, flat idx asc == lax.top_k) => ranks globally unique =>
// winners write out[rank] race-free across blocks. Rows beyond the number
// of valid candidates get defaults, written only by the c==0 block.
__global__ __launch_bounds__(256) void topk_kernel(const float* __restrict__ ws_s,
                                                   const float* __restrict__ ws_b,
                                                   float* __restrict__ out) {
  const int task = blockIdx.x;
  const int b = task / kC;
  const int c = task - b * kC;
  const int tid = threadIdx.x;
  const int lane = tid & 63;
  const float* __restrict__ ss = ws_s + (size_t)b * kFlat;
  const float4* __restrict__ bb4 = (const float4*)ws_b + (size_t)b * kFlat;
  float* __restrict__ ob = out + (size_t)b * kTot * 6;

  __shared__ u64 key[kC * kTot];  // 31.25 KB
  __shared__ int rnk[kTot];
  __shared__ int s_v;

  for (int p = tid; p < kC * kTot; p += 256) {
    const int cc = p / kTot;
    const int i = p - cc * kTot;
    const u32 f = (u32)(cc * kKeep + i);
    key[p] = mkey(ss[f], f);
  }
  for (int i = tid; i < kTot; i += 256) rnk[i] = i;  // own-class count == i
  if (tid == 0) s_v = 0;
  __syncthreads();

  // valid-candidate count (for default rows; usually V >= kTot)
  int myv = 0;
  for (int p = tid; p < kC * kTot; p += 256) myv += (key[p] != 0ull) ? 1 : 0;
#pragma unroll
  for (int off = 32; off; off >>= 1) myv += __shfl_xor(myv, off);
  if (lane == 0) atomicAdd(&s_v, myv);

  // cross-class searches: task t = (candidate i, other-class j)
  const u64* __restrict__ myk = &key[c * kTot];
  for (int t = tid; t < kTot * (kC - 1); t += 256) {
    const int i = t / (kC - 1);
    int c2 = t - i * (kC - 1);
    c2 += (c2 >= c) ? 1 : 0;
    const u64 k = myk[i];
    if (k == 0ull) continue;
    const u64* __restrict__ seg = &key[c2 * kTot];
    int lo = 0, hi = kTot;
    while (lo < hi) {  // count of elements > k in descending-sorted seg
      const int mid = (lo + hi) >> 1;
      if (seg[mid] > k) lo = mid + 1;
      else hi = mid;
    }
    if (lo) atomicAdd(&rnk[i], lo);
  }
  __syncthreads();

  // winners of this class write their rows
  for (int i = tid; i < kTot; i += 256) {
    const u64 k = myk[i];
    if (k == 0ull) continue;
    const int r = rnk[i];
    if (r < kTot) {
      const u32 f = 0xFFFFFFFFu - (u32)(k & 0xFFFFFFFFull);
      const float4 bx = bb4[f];
      ob[r * 6 + 0] = (float)(c + 1);  // class id + 1
      ob[r * 6 + 1] = __uint_as_float((u32)(k >> 32));
      ob[r * 6 + 2] = fminf(fmaxf(bx.x, 0.0f), 1.0f);
      ob[r * 6 + 3] = fminf(fmaxf(bx.y, 0.0f), 1.0f);
      ob[r * 6 + 4] = fminf(fmaxf(bx.z, 0.0f), 1.0f);
      ob[r * 6 + 5] = fminf(fmaxf(bx.w, 0.0f), 1.0f);
    }
  }
  // default rows [min(V,kTot), kTot): exactly the ranks no candidate holds
  if (c == 0) {
    const int v0 = min(s_v, kTot);
    for (int r = v0 + tid; r < kTot; r += 256) {
      ob[r * 6 + 0] = 1.0f;  // class 0 + 1
      ob[r * 6 + 1] = 0.0f;
      ob[r * 6 + 2] = 0.0f;
      ob[r * 6 + 3] = 0.0f;
      ob[r * 6 + 4] = 0.0f;
      ob[r * 6 + 5] = 0.0f;
    }
  }
}

extern "C" void kernel_launch(void* const* d_in, const int* in_sizes, int n_in,
                              void* d_out, int out_size, void* d_ws, size_t ws_size,
                              hipStream_t stream) {
  const float* in = (const float*)d_in[0];
  float* out = (float*)d_out;
  float* ws_s = (float*)d_ws;                      // 96,000 floats
  float* ws_b = ws_s + (size_t)kB * kC * kKeep;    // 384,000 floats
  float* st = ws_b + (size_t)kB * kC * kKeep * 4;  // 2,794,240 floats
  float4* pbox = (float4*)(st + (size_t)kB * kC * kN);  // 139,712 float4
  const size_t needed =
      ((size_t)kB * kC * kKeep * 5 + (size_t)kB * kC * kN + (size_t)kB * kN * 4) *
      sizeof(float);
  if (ws_size >= needed) {
    prep_kernel<<<dim3((kN + 255) / 256, kB), dim3(256), 0, stream>>>(in, st,
                                                                      pbox);
    nms_kernel<true><<<dim3(kB * kC), dim3(TPB), 0, stream>>>(in, st, pbox,
                                                              ws_s, ws_b);
  } else {
    nms_kernel<false><<<dim3(kB * kC), dim3(TPB), 0, stream>>>(
        in, nullptr, nullptr, ws_s, ws_b);
  }
  topk_kernel<<<dim3(kB * kC), dim3(256), 0, stream>>>(ws_s, ws_b, out);
}

// Round 25
// 88.228 us; speedup vs baseline: 1.1891x; 1.1891x over previous
//
#include <hip/hip_runtime.h>

typedef unsigned long long u64;
typedef unsigned int u32;

namespace {
constexpr int kB = 16;
constexpr int kN = 8732;
constexpr int kC = 20;
constexpr int kRow = 25;      // 1 + C + 4
constexpr int kKeep = 300;    // NNS_K (ws stride; reference keeps 300/class)
constexpr int kSel = 200;     // selections that can matter: per-class entries at
                              // list position >= 200 have global rank >= 200 and
                              // can never appear in the top-200 output. Greedy's
                              // first 200 selections depend only on earlier
                              // selections, so stopping at 200 is exact.
constexpr int kTot = 200;     // K_TOTAL
constexpr float kConf = 0.01f;
// fl32(inter/union) > 0.45f  <=>  inter/union > 0.45f + ulp/2 (0.45f mantissa even,
// tie rounds down). kThr = 30198989 * 2^-26 exactly; 26-bit x 24-bit product
// is <= 50 bits -> exact in f64, so the f64 compare is an exact emulation.
constexpr double kThr = 0.45000000298023223876953125;

constexpr int TPB = 512;
constexpr int NW = TPB / 64;                  // 8 waves
constexpr int NBKT = 4096;                    // score buckets (bits>>14);
                                              // shallow buckets (~2.5 deep) keep
                                              // the per-bucket insertion sort's
                                              // serial chain short (r24 lesson)
constexpr int kPool = 512;                    // sorted pool per tranche; rank
                                              // needed for cnt=200 is ~320-360
                                              // at measured p~0.0032 (tranche
                                              // loop keeps exactness regardless)
constexpr int kFlat = kC * kKeep;             // 6000
constexpr int kNIter = (kN + TPB - 1) / TPB;  // 18
}

// exact emulation of reference: (union>0) && fl32(inter/union) > 0.45f
// (union >= 0 provable by rounding monotonicity; union==0 => inter==0 => false)
// box layout: float4 = (y1, x1, y2, x2)
__device__ __forceinline__ bool iou_gt4(const float4 a, const float aa,
                                        const float4 b, const float ba) {
  const float ty1 = fmaxf(a.x, b.x);
  const float tx1 = fmaxf(a.y, b.y);
  const float ty2 = fminf(a.z, b.z);
  const float tx2 = fminf(a.w, b.w);
  const float dy = fmaxf(__fsub_rn(ty2, ty1), 0.0f);
  const float dx = fmaxf(__fsub_rn(tx2, tx1), 0.0f);
  const float inter = __fmul_rn(dy, dx);
  const float uni = __fsub_rn(__fadd_rn(aa, ba), inter);
  return ((double)inter > kThr * (double)uni);
}

// bucket by high bits of score: monotone DESC (bucket 0 = highest scores).
__device__ __forceinline__ int bkt_of(float s) {
  return 65024 - (int)(__float_as_uint(s) >> 14);
}
// packed in-bucket key: (low14 desc, 16383-idx desc) == (score desc, idx asc)
__device__ __forceinline__ u32 key_of(float s, int idx) {
  return ((__float_as_uint(s) & 0x3FFFu) << 14) | (u32)(16383 - idx);
}
// full-order u64 merge key: (score desc, flat idx asc); 0 == empty
__device__ __forceinline__ u64 mkey(float s, u32 f) {
  return (s > 0.0f) ? ((((u64)__float_as_uint(s)) << 32) | (u64)(0xFFFFFFFFu - f))
                    : 0ull;
}

// exclusive prefix sum over hist[NBKT]; 512 threads own 8 buckets each.
__device__ int excl_scan_hist(u32* hist, u32* wsum, int tid) {
  const int base = tid * 8;
  u32 loc[8];
  u32 s = 0;
#pragma unroll
  for (int i = 0; i < 8; ++i) { loc[i] = hist[base + i]; s += loc[i]; }
  int v = (int)s;
  const int lane = tid & 63;
#pragma unroll
  for (int off = 1; off < 64; off <<= 1) {
    const int u = __shfl_up(v, off);
    if (lane >= off) v += u;
  }
  if (lane == 63) wsum[tid >> 6] = (u32)v;
  __syncthreads();
  u32 woff = 0, total = 0;
#pragma unroll
  for (int w = 0; w < NW; ++w) {
    const u32 t = wsum[w];
    total += t;
    if (w < (tid >> 6)) woff += t;
  }
  u32 run = woff + (u32)v - s;
#pragma unroll
  for (int i = 0; i < 8; ++i) { hist[base + i] = run; run += loc[i]; }
  __syncthreads();
  return (int)total;
}

// Transpose pass: scores_t[b][c][n] + packed float4 boxes pbox[b][n].
__global__ __launch_bounds__(256) void prep_kernel(const float* __restrict__ in,
                                                   float* __restrict__ st,
                                                   float4* __restrict__ pbox) {
  const int b = blockIdx.y;
  const int n0 = blockIdx.x * 256;
  const int tid = threadIdx.x;
  const int rows = min(256, kN - n0);

  __shared__ float tile[256 * kRow];
  const float* __restrict__ src = in + ((size_t)b * kN + n0) * kRow;
  const int total = rows * kRow;
  for (int i = tid; i < total; i += 256) tile[i] = src[i];
  __syncthreads();
  if (tid < rows) {
    const int n = n0 + tid;
    const float* row = &tile[tid * kRow];
#pragma unroll
    for (int c = 0; c < kC; ++c)
      st[((size_t)b * kC + c) * kN + n] = row[1 + c];
    pbox[(size_t)b * kN + n] = make_float4(row[21], row[22], row[23], row[24]);
  }
}

// One block per (b,c) task. Phase 1 (per tranche): bucket-CDF window of top
// <=512 candidates, scatter + tiny in-bucket insertion sorts -> exact
// (score desc, idx asc) pool; boxes/areas/scores prefetched to LDS.
// Phase 2: groups of 64; all 512 threads compute sup-vs-selected + in-group
// kill rows; wave 0 resolves. Scan stops at kSel=200 selections (exact:
// later selections cannot affect the top-200 output).
template <bool X>
__global__ __launch_bounds__(TPB, 4) void nms_kernel(const float* __restrict__ in,
                                                     const float* __restrict__ st,
                                                     const float4* __restrict__ pbox,
                                                     float* __restrict__ ws_s,
                                                     float* __restrict__ ws_b) {
  const int task = blockIdx.x;
  const int b = task / kC;
  const int c = task - b * kC;
  const int tid = threadIdx.x;
  const float* __restrict__ base_in = in + (size_t)b * kN * kRow;
  const float* __restrict__ stc = st + ((size_t)b * kC + c) * kN;
  const size_t bo = (size_t)b * kN;

  __shared__ __align__(16) unsigned char ovl[16384];  // hist(16K) | pool(12K)
  __shared__ u32 skey[kPool];                         // 2 KB
  __shared__ float4 sel_box[kSel];                    // 3.2 KB
  __shared__ float sel_ar[kSel];                      // 0.8 KB
  __shared__ float sel_sc[kSel];                      // 0.8 KB
  __shared__ u32 supp8[NW * 64];                      // 2 KB
  __shared__ u64 grp8[NW * 64];                       // 4 KB
  __shared__ u32 wsum[NW];
  __shared__ int s_red[NW];
  __shared__ int s_nc;

  u32* hist = (u32*)ovl;
  float4* gbox = (float4*)ovl;          // 512 * 16 = 8 KB
  float* gar = (float*)(ovl + 8192);    // 2 KB
  float* gsc = (float*)(ovl + 10240);   // 2 KB

  const int lane = tid & 63;
  const int wid = tid >> 6;

  int cnt = 0;
  int blo = 0;
  while (cnt < kSel && blo < NBKT) {
    // ---- histogram (scores re-read from the coalesced L2-hot column) ----
    for (int i = tid; i < NBKT; i += TPB) hist[i] = 0;
    __syncthreads();
    for (int k = 0; k < kNIter; ++k) {
      const int n = tid + k * TPB;
      if (n < kN) {
        const float s = X ? stc[n] : base_in[(size_t)n * kRow + 1 + c];
        if (s > kConf) atomicAdd(&hist[bkt_of(s)], 1u);
      }
    }
    __syncthreads();
    const int ncand = excl_scan_hist(hist, wsum, tid);
    const int base = (int)hist[blo];
    if (ncand == 0 || base >= ncand) break;
    // ---- bend: max bucket bound with window count <= kPool ----
    int bestb = blo + 1;
#pragma unroll
    for (int i = 0; i < 8; ++i) {
      const int bb = tid * 8 + i;
      if (bb > blo && (int)hist[bb] - base <= kPool) bestb = max(bestb, bb);
    }
    if (ncand - base <= kPool) bestb = NBKT;
#pragma unroll
    for (int off = 32; off; off >>= 1) bestb = max(bestb, __shfl_xor(bestb, off));
    if (lane == 0) s_red[wid] = bestb;
    __syncthreads();
    int bend = s_red[0];
#pragma unroll
    for (int w = 1; w < NW; ++w) bend = max(bend, s_red[w]);
    const int poolN =
        min(((bend == NBKT) ? ncand : (int)hist[bend]) - base, kPool);
    // ---- scatter window [blo, bend) ----
    for (int k = 0; k < kNIter; ++k) {
      const int n = tid + k * TPB;
      if (n < kN) {
        const float s = X ? stc[n] : base_in[(size_t)n * kRow + 1 + c];
        if (s > kConf) {
          const int bb = bkt_of(s);
          if (bb >= blo && bb < bend) {
            const u32 pos = atomicAdd(&hist[bb], 1u) - (u32)base;
            if (pos < (u32)kPool) skey[pos] = key_of(s, n);
          }
        }
      }
    }
    __syncthreads();
    // ---- in-bucket insertion sort (desc u32 key) ----
    for (int bb = blo + tid; bb < bend; bb += TPB) {
      int s0 = (bb == blo) ? 0 : (int)hist[bb - 1] - base;
      int e0 = (int)hist[bb] - base;
      s0 = min(s0, kPool);
      e0 = min(e0, kPool);
      for (int i = s0 + 1; i < e0; ++i) {
        const u32 kk = skey[i];
        int j = i - 1;
        while (j >= s0 && kk > skey[j]) { skey[j + 1] = skey[j]; --j; }
        skey[j + 1] = kk;
      }
    }
    __syncthreads();  // hist dead -> pool arrays overlay it
    // ---- pool prefetch: boxes, areas, scores ----
    for (int i = tid; i < poolN; i += TPB) {
      const int eidx = 16383 - (int)(skey[i] & 0x3FFFu);
      float4 bx;
      float s;
      if (X) {
        bx = pbox[bo + eidx];
        s = stc[eidx];
      } else {
        const float* r = base_in + (size_t)eidx * kRow;
        bx = make_float4(r[21], r[22], r[23], r[24]);
        s = r[1 + c];
      }
      gbox[i] = bx;
      gar[i] = __fmul_rn(__fsub_rn(bx.z, bx.x), __fsub_rn(bx.w, bx.y));
      gsc[i] = s;
    }
    __syncthreads();

    // ---- phase 2: groups of 64 ----
    int g0 = 0;
    while (cnt < kSel && g0 < poolN) {
      const int i = g0 + lane;
      u32 sup = 1u;
      u64 rowbits = 0;
      if (i < poolN) {
        sup = 0u;
        const float4 eb = gbox[i];
        const float ea = gar[i];
        for (int j = wid; j < cnt; j += NW)
          sup |= iou_gt4(eb, ea, sel_box[j], sel_ar[j]) ? 1u : 0u;
        for (int t2 = wid; t2 < lane; t2 += NW)
          rowbits |= iou_gt4(eb, ea, gbox[g0 + t2], gar[g0 + t2])
                         ? (1ull << t2)
                         : 0ull;
      }
      supp8[wid * 64 + lane] = sup;
      grp8[wid * 64 + lane] = rowbits;
      __syncthreads();  // A: partials visible
      if (tid < 64) {   // wave 0 resolve (exact sequential-greedy semantics)
        u32 sp = 0;
        u64 row = 0;
#pragma unroll
        for (int s2 = 0; s2 < NW; ++s2) {
          sp |= supp8[s2 * 64 + tid];
          row |= grp8[s2 * 64 + tid];
        }
        const u64 pend = __ballot(sp == 0u);
        u64 acc = 0;
        int nc = cnt;
        if (cnt + __popcll(pend) <= kSel) {
          // cap-free: mass-accept unconstrained (row==0) lanes; serial walk
          // only the constrained ones (ascending == rank order).
          const u64 consb = __ballot(row != 0ull);
          acc = pend & ~consb;
          u64 rem = pend & consb;
          while (rem != 0ull) {
            const int cur = __ffsll(rem) - 1;
            const u64 cb = 1ull << cur;
            const u64 rcur = __shfl(row, cur);  // row bits only cover earlier lanes
            if ((rcur & acc) == 0ull) acc |= cb;
            rem &= ~cb;
          }
          nc = cnt + (int)__popcll(acc);
        } else {
          // near the kSel cap: exact capped serial walk (accepts in rank
          // order; the first 200 accepts are exactly greedy's first 200)
          u64 pend2 = pend;
          while (pend2 != 0ull && nc < kSel) {
            const int cur = __ffsll(pend2) - 1;
            const u64 cb = 1ull << cur;
            acc |= cb;
            ++nc;
            const u64 killed = __ballot(((row >> cur) & 1ull) != 0ull);
            pend2 &= ~(killed | cb);
          }
        }
        if ((acc >> tid) & 1ull) {
          const int slot = cnt + (int)__popcll(acc & ((1ull << tid) - 1ull));
          const int ii = g0 + tid;
          sel_box[slot] = gbox[ii];
          sel_ar[slot] = gar[ii];
          sel_sc[slot] = gsc[ii];
        }
        if (tid == 0) s_nc = nc;
      }
      __syncthreads();  // B: sel + s_nc visible
      cnt = s_nc;
      g0 += 64;
    }
    blo = bend;
  }

  // ---- final writeout (slots [cnt, 300) = empty; topk reads only [0,200)) ----
  float* __restrict__ out_s = ws_s + (size_t)task * kKeep;
  float* __restrict__ out_b = ws_b + (size_t)task * kKeep * 4;
  for (int i = tid; i < kKeep; i += TPB) {
    if (i < cnt) {
      out_s[i] = sel_sc[i];
      *(float4*)&out_b[(size_t)i * 4] = sel_box[i];
    } else {
      out_s[i] = -1.0f;
    }
  }
}

// One 256-thread block per (b, c): top-200 by merge-rank with the 19
// cross-class binary searches of each candidate done by DIFFERENT threads
// (independent, latency-overlapped), ranks summed via LDS atomicAdd.
// Only the first kTot entries per class can reach the top-200 (position i
// has i better elements in its own list). Keys are a strict total order
// (score desc, flat idx asc == lax.top_k) => ranks globally unique =>
// winners write out[rank] race-free across blocks. Rows beyond the number
// of valid candidates get defaults, written only by the c==0 block.
__global__ __launch_bounds__(256) void topk_kernel(const float* __restrict__ ws_s,
                                                   const float* __restrict__ ws_b,
                                                   float* __restrict__ out) {
  const int task = blockIdx.x;
  const int b = task / kC;
  const int c = task - b * kC;
  const int tid = threadIdx.x;
  const int lane = tid & 63;
  const float* __restrict__ ss = ws_s + (size_t)b * kFlat;
  const float4* __restrict__ bb4 = (const float4*)ws_b + (size_t)b * kFlat;
  float* __restrict__ ob = out + (size_t)b * kTot * 6;

  __shared__ u64 key[kC * kTot];  // 31.25 KB
  __shared__ int rnk[kTot];
  __shared__ int s_v;

  for (int p = tid; p < kC * kTot; p += 256) {
    const int cc = p / kTot;
    const int i = p - cc * kTot;
    const u32 f = (u32)(cc * kKeep + i);
    key[p] = mkey(ss[f], f);
  }
  for (int i = tid; i < kTot; i += 256) rnk[i] = i;  // own-class count == i
  if (tid == 0) s_v = 0;
  __syncthreads();

  // valid-candidate count (for default rows; usually V >= kTot)
  int myv = 0;
  for (int p = tid; p < kC * kTot; p += 256) myv += (key[p] != 0ull) ? 1 : 0;
#pragma unroll
  for (int off = 32; off; off >>= 1) myv += __shfl_xor(myv, off);
  if (lane == 0) atomicAdd(&s_v, myv);

  // cross-class searches: task t = (candidate i, other-class j)
  const u64* __restrict__ myk = &key[c * kTot];
  for (int t = tid; t < kTot * (kC - 1); t += 256) {
    const int i = t / (kC - 1);
    int c2 = t - i * (kC - 1);
    c2 += (c2 >= c) ? 1 : 0;
    const u64 k = myk[i];
    if (k == 0ull) continue;
    const u64* __restrict__ seg = &key[c2 * kTot];
    int lo = 0, hi = kTot;
    while (lo < hi) {  // count of elements > k in descending-sorted seg
      const int mid = (lo + hi) >> 1;
      if (seg[mid] > k) lo = mid + 1;
      else hi = mid;
    }
    if (lo) atomicAdd(&rnk[i], lo);
  }
  __syncthreads();

  // winners of this class write their rows
  for (int i = tid; i < kTot; i += 256) {
    const u64 k = myk[i];
    if (k == 0ull) continue;
    const int r = rnk[i];
    if (r < kTot) {
      const u32 f = 0xFFFFFFFFu - (u32)(k & 0xFFFFFFFFull);
      const float4 bx = bb4[f];
      ob[r * 6 + 0] = (float)(c + 1);  // class id + 1
      ob[r * 6 + 1] = __uint_as_float((u32)(k >> 32));
      ob[r * 6 + 2] = fminf(fmaxf(bx.x, 0.0f), 1.0f);
      ob[r * 6 + 3] = fminf(fmaxf(bx.y, 0.0f), 1.0f);
      ob[r * 6 + 4] = fminf(fmaxf(bx.z, 0.0f), 1.0f);
      ob[r * 6 + 5] = fminf(fmaxf(bx.w, 0.0f), 1.0f);
    }
  }
  // default rows [min(V,kTot), kTot): exactly the ranks no candidate holds
  if (c == 0) {
    const int v0 = min(s_v, kTot);
    for (int r = v0 + tid; r < kTot; r += 256) {
      ob[r * 6 + 0] = 1.0f;  // class 0 + 1
      ob[r * 6 + 1] = 0.0f;
      ob[r * 6 + 2] = 0.0f;
      ob[r * 6 + 3] = 0.0f;
      ob[r * 6 + 4] = 0.0f;
      ob[r * 6 + 5] = 0.0f;
    }
  }
}

extern "C" void kernel_launch(void* const* d_in, const int* in_sizes, int n_in,
                              void* d_out, int out_size, void* d_ws, size_t ws_size,
                              hipStream_t stream) {
  const float* in = (const float*)d_in[0];
  float* out = (float*)d_out;
  float* ws_s = (float*)d_ws;                      // 96,000 floats
  float* ws_b = ws_s + (size_t)kB * kC * kKeep;    // 384,000 floats
  float* st = ws_b + (size_t)kB * kC * kKeep * 4;  // 2,794,240 floats
  float4* pbox = (float4*)(st + (size_t)kB * kC * kN);  // 139,712 float4
  const size_t needed =
      ((size_t)kB * kC * kKeep * 5 + (size_t)kB * kC * kN + (size_t)kB * kN * 4) *
      sizeof(float);
  if (ws_size >= needed) {
    prep_kernel<<<dim3((kN + 255) / 256, kB), dim3(256), 0, stream>>>(in, st,
                                                                      pbox);
    nms_kernel<true><<<dim3(kB * kC), dim3(TPB), 0, stream>>>(in, st, pbox,
                                                              ws_s, ws_b);
  } else {
    nms_kernel<false><<<dim3(kB * kC), dim3(TPB), 0, stream>>>(
        in, nullptr, nullptr, ws_s, ws_b);
  }
  topk_kernel<<<dim3(kB * kC), dim3(256), 0, stream>>>(ws_s, ws_b, out);
}